// Round 13
// baseline (166.340 us; speedup 1.0000x reference)
//
#include <hip/hip_runtime.h>
#include <hip/hip_fp16.h>

#define D 128
#define LN_EPS 1e-5f

// Dtypes (R0-R7 forensics): x,W,b,gamma,beta fp32; edge_index int32; out fp32.
// R8 234 -> R10 177.7 (counting sort) -> R12 154.4 (fused no-LDS W: 49.4us,
// occ 43%, VGPR 32; aux ~105us over 4 small dispatches).
// R13: (1) whole CSR build in ONE dispatch (64 blocks + device-scope grid
// barriers, CG-style); (2) fused: 2 waves/node edge-split (20000 waves).

static __device__ __forceinline__ float h2f(unsigned short h) {
    return __half2float(__builtin_bit_cast(__half, h));
}
static __device__ __forceinline__ unsigned short f2h(float f) {
    return __builtin_bit_cast(unsigned short, __float2half_rn(f));
}

// device-scope grid barrier (counter pre-zeroed by host memset; used once each)
static __device__ __forceinline__ void gbar(int* cnt, int target) {
    __syncthreads();
    if (threadIdx.x == 0) {
        __hip_atomic_fetch_add(cnt, 1, __ATOMIC_RELEASE, __HIP_MEMORY_SCOPE_AGENT);
        while (__hip_atomic_load(cnt, __ATOMIC_ACQUIRE, __HIP_MEMORY_SCOPE_AGENT) < target) {
            __builtin_amdgcn_s_sleep(1);
        }
    }
    __syncthreads();
}

// ---- B: entire CSR build + fp16 convert, one dispatch, C blocks ----
// P0 convert x,W + per-chunk LDS hist -> ghist | P1 chunk-offsets + deg + local
// scan | P2 cross-block prefix -> rowptr | P3 scatter with LDS cursors.
__global__ __launch_bounds__(1024) void build_kernel(
        const int* __restrict__ src, const int* __restrict__ dst,
        const float* __restrict__ x, const float* __restrict__ W,
        unsigned int* __restrict__ xh, unsigned int* __restrict__ Wh,
        int* __restrict__ ghist, int* __restrict__ blocksum,
        int* __restrict__ rowptr, float* __restrict__ dinv,
        unsigned short* __restrict__ csr, int* __restrict__ bar,
        int N, int E, int Ec, int NH, int NW, int C) {
    extern __shared__ int lds[];           // N ints (40 KB)
    int c = blockIdx.x;
    int tid = threadIdx.x;
    int lane = tid & 63, wv = tid >> 6;

    // P0: zero hist, convert (grid-strided), histogram my chunk
    for (int i = tid; i < N; i += 1024) lds[i] = 0;
    int gs = gridDim.x * 1024;
    int tot = NH + NW;
    for (int i = c * 1024 + tid; i < tot; i += gs) {
        if (i < NH) {
            float2 v = ((const float2*)x)[i];
            xh[i] = (unsigned int)f2h(v.x) | ((unsigned int)f2h(v.y) << 16);
        } else {
            float2 v = ((const float2*)W)[i - NH];
            Wh[i - NH] = (unsigned int)f2h(v.x) | ((unsigned int)f2h(v.y) << 16);
        }
    }
    __syncthreads();
    int lo = c * Ec, hi = min(lo + Ec, E);
    for (int i = lo + tid; i < hi; i += 1024)
        atomicAdd(&lds[dst[i]], 1);        // LDS atomic
    __syncthreads();
    for (int i = tid; i < N; i += 1024) ghist[c * N + i] = lds[i];
    gbar(bar + 0, C);

    // P1: my node range: exclusive over chunks (in-place) -> deg, dinv, local scan
    int nper = (N + C - 1) / C;
    int n0 = c * nper;
    int nn = min(nper, N - n0); if (nn < 0) nn = 0;
    int mydeg = 0;
    if (tid < nn) {
        int n = n0 + tid;
        int run = 0;
        #pragma unroll 8
        for (int cc = 0; cc < C; cc++) {   // loads independent -> pipeline
            int t = ghist[cc * N + n];
            ghist[cc * N + n] = run;
            run += t;
        }
        mydeg = run;
        dinv[n] = rsqrtf((float)(run + 1));   // +1 self-loop
    }
    // block scan of mydeg over 1024 threads (valid for tid<nn; zeros elsewhere)
    int incl = mydeg;
    #pragma unroll
    for (int off = 1; off < 64; off <<= 1) {
        int y = __shfl_up(incl, off);
        if (lane >= off) incl += y;
    }
    __syncthreads();                        // lds reuse guard
    if (lane == 63) lds[wv] = incl;
    __syncthreads();
    if (tid == 0) {
        int run = 0;
        #pragma unroll
        for (int k = 0; k < 16; k++) { int t = lds[k]; lds[k] = run; run += t; }
        lds[16] = run;                      // block total
    }
    __syncthreads();
    int excl = lds[wv] + incl - mydeg;
    if (tid < nn) rowptr[n0 + tid] = excl;  // local prefix; base added in P2
    if (tid == 0) blocksum[c] = lds[16];
    gbar(bar + 1, C);

    // P2: cross-block exclusive prefix (C <= 64 -> one wave)
    __syncthreads();
    if (wv == 0) {
        int bs = (lane < C) ? blocksum[lane] : 0;
        int inc2 = bs;
        #pragma unroll
        for (int off = 1; off < 64; off <<= 1) {
            int y = __shfl_up(inc2, off);
            if (lane >= off) inc2 += y;
        }
        if (lane == C - 1) lds[17] = inc2;  // grand total
        if (lane == c)     lds[18] = inc2 - bs;  // my base
    }
    __syncthreads();
    int base = lds[18];
    if (tid < nn) rowptr[n0 + tid] += base;
    if (c == C - 1 && tid == 0) rowptr[N] = lds[17];
    gbar(bar + 2, C);

    // P3: scatter my chunk with LDS cursors; 2B stores, zero global atomics
    for (int i = tid; i < N; i += 1024) lds[i] = rowptr[i] + ghist[c * N + i];
    __syncthreads();
    for (int i = lo + tid; i < hi; i += 1024) {
        int d = dst[i];
        int pos = atomicAdd(&lds[d], 1);
        csr[pos] = (unsigned short)src[i];
    }
}

// ---- fused2: 2 waves per node (edge-split) -> linear (fp16 W, L1) -> LN ----
__global__ __launch_bounds__(512) void fused2(const unsigned int* __restrict__ xh,
                                              const unsigned int* __restrict__ Wh,
                                              const int* __restrict__ rowptr,
                                              const unsigned short* __restrict__ csr,
                                              const float* __restrict__ dinv,
                                              const float* __restrict__ bias,
                                              const float* __restrict__ gamma,
                                              const float* __restrict__ beta,
                                              float* __restrict__ out, int N) {
    __shared__ float sAgg[4][D];           // full agg per node slot
    __shared__ float sRed[4][2][2];        // LN partials [slot][half][sum,sq]
    int wv = threadIdx.x >> 6, lane = threadIdx.x & 63;
    int pair = wv >> 1, half = wv & 1;
    int node = blockIdx.x * 4 + pair;
    bool valid = (node < N);
    int node_c = valid ? node : (N - 1);
    float dn = dinv[node_c];

    // partial aggregate over my half of the edge chunks (stride 128)
    float a0 = 0.f, a1 = 0.f;
    if (half == 0) {                       // self-loop on half 0
        unsigned int xv = xh[node_c * 64 + lane];
        a0 = h2f((unsigned short)xv) * dn * dn;
        a1 = h2f((unsigned short)(xv >> 16)) * dn * dn;
    }
    int start = rowptr[node_c], end = rowptr[node_c + 1];
    for (int bs = start + half * 64; bs < end; bs += 128) {
        int cnt = min(64, end - bs);
        if (cnt == 64) {
            int s = csr[bs + lane];
            float wt = dinv[s] * dn;
            #pragma unroll 8
            for (int k = 0; k < 64; k++) {
                int sk = __shfl(s, k);
                float wk = __shfl(wt, k);
                unsigned int hv = xh[sk * 64 + lane];
                a0 += h2f((unsigned short)hv) * wk;
                a1 += h2f((unsigned short)(hv >> 16)) * wk;
            }
        } else {
            int s = 0; float wt = 0.f;
            if (lane < cnt) { s = csr[bs + lane]; wt = dinv[s] * dn; }
            for (int k = 0; k < cnt; k++) {
                int sk = __shfl(s, k);
                float wk = __shfl(wt, k);
                unsigned int hv = xh[sk * 64 + lane];
                a0 += h2f((unsigned short)hv) * wk;
                a1 += h2f((unsigned short)(hv >> 16)) * wk;
            }
        }
    }
    // combine halves into sAgg (ordered by barrier; 2-way LDS aliasing is free)
    if (half == 0) { sAgg[pair][2 * lane] = a0; sAgg[pair][2 * lane + 1] = a1; }
    __syncthreads();
    if (half == 1) { sAgg[pair][2 * lane] += a0; sAgg[pair][2 * lane + 1] += a1; }
    __syncthreads();

    // linear: my wave owns 64 output cols c = half*64 + lane; W fp16 from L1
    const unsigned short* Wh16 = (const unsigned short*)Wh;
    int cc = half * 64 + lane;
    float y = bias[cc];
    #pragma unroll 8
    for (int k = 0; k < D; k++)
        y += sAgg[pair][k] * h2f(Wh16[k * D + cc]);   // LDS broadcast + L1 hit

    // LayerNorm over 128 (two wave-partials)
    float sum = y, sq = y * y;
    #pragma unroll
    for (int off = 32; off > 0; off >>= 1) {
        sum += __shfl_xor(sum, off);
        sq  += __shfl_xor(sq, off);
    }
    if (lane == 0) { sRed[pair][half][0] = sum; sRed[pair][half][1] = sq; }
    __syncthreads();
    float tsum = sRed[pair][0][0] + sRed[pair][1][0];
    float tsq  = sRed[pair][0][1] + sRed[pair][1][1];
    float mean = tsum * (1.0f / D);
    float var  = tsq * (1.0f / D) - mean * mean;
    float inv  = rsqrtf(var + LN_EPS);
    float o = (y - mean) * inv * gamma[cc] + beta[cc];
    if (valid) out[(size_t)node * D + cc] = o;
}

// ================= fallback (R8, proven): used only if ws too small =========

__global__ void deg_kernel(const int* __restrict__ dst, int* __restrict__ deg, int E) {
    int e = blockIdx.x * blockDim.x + threadIdx.x;
    if (e < E) atomicAdd(&deg[dst[e]], 1);
}
__global__ __launch_bounds__(1024) void scan_kernel(const int* __restrict__ deg,
                                                    int* __restrict__ rowptr,
                                                    int* __restrict__ fill,
                                                    float* __restrict__ dinv, int N) {
    __shared__ int s_wsum[16];
    __shared__ int s_woff[16];
    __shared__ int s_carry;
    int t = threadIdx.x;
    int lane = t & 63, w = t >> 6;
    if (t == 0) s_carry = 0;
    __syncthreads();
    for (int base = 0; base < N; base += 1024) {
        int i = base + t;
        int v = (i < N) ? deg[i] : 0;
        int incl = v;
        #pragma unroll
        for (int off = 1; off < 64; off <<= 1) {
            int y = __shfl_up(incl, off);
            if (lane >= off) incl += y;
        }
        if (lane == 63) s_wsum[w] = incl;
        __syncthreads();
        if (t == 0) {
            int run = s_carry;
            #pragma unroll
            for (int k = 0; k < 16; k++) { s_woff[k] = run; run += s_wsum[k]; }
            s_carry = run;
        }
        __syncthreads();
        if (i < N) {
            int rp = s_woff[w] + (incl - v);
            rowptr[i] = rp;
            fill[i] = rp;
            dinv[i] = rsqrtf((float)(v + 1));
        }
    }
    if (t == 0) rowptr[N] = s_carry;
}
__global__ void fill_kernel(const int* __restrict__ src, const int* __restrict__ dst,
                            int* __restrict__ fill, unsigned short* __restrict__ csr, int E) {
    int e = blockIdx.x * blockDim.x + threadIdx.x;
    if (e < E) {
        int pos = atomicAdd(&fill[dst[e]], 1);
        csr[pos] = (unsigned short)src[e];
    }
}
__global__ __launch_bounds__(512) void fused_fp32(const float* __restrict__ x,
                                                  const float* __restrict__ W,
                                                  const int* __restrict__ rowptr,
                                                  const unsigned short* __restrict__ csr,
                                                  const float* __restrict__ dinv,
                                                  const float* __restrict__ bias,
                                                  const float* __restrict__ gamma,
                                                  const float* __restrict__ beta,
                                                  float* __restrict__ out, int N) {
    __shared__ float sW[D * D];
    {
        const float4* Wv = (const float4*)W;
        float4* sWv = (float4*)sW;
        #pragma unroll
        for (int i = 0; i < (D * D / 4) / 512; i++)
            sWv[threadIdx.x + i * 512] = Wv[threadIdx.x + i * 512];
    }
    __syncthreads();
    int w = threadIdx.x >> 6, lane = threadIdx.x & 63;
    int node = blockIdx.x * 8 + w;
    if (node >= N) return;
    float dn = dinv[node];
    int c0 = lane * 2;
    float2 xv = *(const float2*)(x + (size_t)node * D + c0);
    float a0 = xv.x * dn * dn, a1 = xv.y * dn * dn;
    int start = rowptr[node], end = rowptr[node + 1];
    int base = start;
    for (; base + 64 <= end; base += 64) {
        int s = csr[base + lane];
        float wt = dinv[s] * dn;
        #pragma unroll 8
        for (int k = 0; k < 64; k++) {
            int sk = __shfl(s, k);
            float wk = __shfl(wt, k);
            float2 xs = *(const float2*)(x + (size_t)sk * D + c0);
            a0 += xs.x * wk; a1 += xs.y * wk;
        }
    }
    int rem = end - base;
    if (rem > 0) {
        int s = 0; float wt = 0.f;
        if (lane < rem) { s = csr[base + lane]; wt = dinv[s] * dn; }
        for (int k = 0; k < rem; k++) {
            int sk = __shfl(s, k);
            float wk = __shfl(wt, k);
            float2 xs = *(const float2*)(x + (size_t)sk * D + c0);
            a0 += xs.x * wk; a1 += xs.y * wk;
        }
    }
    float y0 = bias[c0], y1 = bias[c0 + 1];
    #pragma unroll 8
    for (int k = 0; k < 64; k++) {
        float g0 = __shfl(a0, k);
        float g1 = __shfl(a1, k);
        float2 w0 = *(const float2*)(sW + (2 * k) * D + c0);
        float2 w1 = *(const float2*)(sW + (2 * k + 1) * D + c0);
        y0 += g0 * w0.x + g1 * w1.x;
        y1 += g0 * w0.y + g1 * w1.y;
    }
    float sum = y0 + y1, sq = y0 * y0 + y1 * y1;
    #pragma unroll
    for (int off = 32; off > 0; off >>= 1) {
        sum += __shfl_xor(sum, off);
        sq  += __shfl_xor(sq, off);
    }
    float mean = sum * (1.0f / D);
    float var  = sq * (1.0f / D) - mean * mean;
    float inv  = rsqrtf(var + LN_EPS);
    float o0 = (y0 - mean) * inv * gamma[c0] + beta[c0];
    float o1 = (y1 - mean) * inv * gamma[c0 + 1] + beta[c0 + 1];
    *(float2*)(out + (size_t)node * D + c0) = make_float2(o0, o1);
}

extern "C" void kernel_launch(void* const* d_in, const int* in_sizes, int n_in,
                              void* d_out, int out_size, void* d_ws, size_t ws_size,
                              hipStream_t stream) {
    const float* x     = (const float*)d_in[0];
    const int*   ei    = (const int*)d_in[1];
    const float* W     = (const float*)d_in[2];
    const float* bias  = (const float*)d_in[3];
    const float* gamma = (const float*)d_in[4];
    const float* beta  = (const float*)d_in[5];
    float*       out   = (float*)d_out;

    int N = in_sizes[0] / D;
    int E = in_sizes[1] / 2;
    const int* src = ei;
    const int* dst = ei + E;

    char* ws = (char*)d_ws;
    size_t off = 0;
    auto carve = [&](size_t bytes) { size_t p = off; off = (off + bytes + 15) & ~15UL; return (void*)(ws + p); };
    int*            bar      = (int*)           carve(64);
    int*            blocksum = (int*)           carve(64 * 4);
    int*            rowptr   = (int*)           carve((size_t)(N + 1) * 4);
    float*          dinv     = (float*)         carve((size_t)N * 4);
    unsigned short* csr      = (unsigned short*)carve((size_t)E * 2);
    unsigned int*   xh       = (unsigned int*)  carve((size_t)N * (D / 2) * 4);
    unsigned int*   Wh       = (unsigned int*)  carve((size_t)D * (D / 2) * 4);
    size_t fixed_end = off;

    // chunk count C = grid of build_kernel; each chunk needs N*4 B of ghist.
    // C in [16,64]: cross-block prefix fits one wave; nper <= 1024.
    int C = 0;
    if (ws_size > fixed_end + 16) {
        size_t avail = ws_size - fixed_end - 16;
        size_t cmax = avail / ((size_t)N * 4);
        C = (int)((cmax > 64) ? 64 : cmax);
    }

    if (C >= 16) {
        int* ghist = (int*)carve((size_t)C * N * 4);
        int Ec = (E + C - 1) / C;
        int NH = N * (D / 2);
        int NW = D * (D / 2);
        size_t lds = (size_t)N * 4;
        hipMemsetAsync(bar, 0, 64, stream);
        build_kernel<<<C, 1024, lds, stream>>>(src, dst, x, W, xh, Wh, ghist,
                                               blocksum, rowptr, dinv, csr, bar,
                                               N, E, Ec, NH, NW, C);
        fused2<<<(N + 3) / 4, 512, 0, stream>>>(xh, Wh, rowptr, csr, dinv,
                                                bias, gamma, beta, out, N);
    } else {
        // fallback: proven R8 path (global-atomic CSR + fp32 fused)
        int* deg  = (int*)carve((size_t)N * 4);
        int* fill = (int*)carve((size_t)N * 4);
        hipMemsetAsync(deg, 0, (size_t)N * 4, stream);
        deg_kernel<<<(E + 255) / 256, 256, 0, stream>>>(dst, deg, E);
        scan_kernel<<<1, 1024, 0, stream>>>(deg, rowptr, fill, dinv, N);
        fill_kernel<<<(E + 255) / 256, 256, 0, stream>>>(src, dst, fill, csr, E);
        fused_fp32<<<(N + 7) / 8, 512, 0, stream>>>(x, W, rowptr, csr, dinv,
                                                    bias, gamma, beta, out, N);
    }
}

// Round 14
// 160.194 us; speedup vs baseline: 1.0384x; 1.0384x over previous
//
#include <hip/hip_runtime.h>
#include <hip/hip_fp16.h>

#define D 128
#define LN_EPS 1e-5f

// Dtypes (R0-R7 forensics): x,W,b,gamma,beta fp32; edge_index int32; out fp32.
// R8 234 | R10 177.7 (counting sort) | R12 154.4 (fused 49.4: no-LDS W, occ 43%)
// R13 166.3 REGRESS: 2-wave/node coupled waves (60us, VALUBusy down). Lesson:
// independent waves + deeper per-wave MLP. R14: uniform predicated 64-chunks
// (kills serial remainder), csr32 with precomputed fp16 wt, readlane broadcasts
// (SGPR-addressed row gathers), single-dispatch build kept.

static __device__ __forceinline__ float h2f(unsigned short h) {
    return __half2float(__builtin_bit_cast(__half, h));
}
static __device__ __forceinline__ unsigned short f2h(float f) {
    return __builtin_bit_cast(unsigned short, __float2half_rn(f));
}

// exact-match flag barrier: phase p uses its own 64-slot array; host zeroes once.
static __device__ __forceinline__ void flagbar(int* slots, int c, int C, int phase) {
    __syncthreads();
    int val = 0x5A5A0001 + phase;
    int tid = threadIdx.x;
    if (tid == 0)
        __hip_atomic_store(&slots[phase * 64 + c], val, __ATOMIC_RELEASE, __HIP_MEMORY_SCOPE_AGENT);
    if (tid < C) {
        while (__hip_atomic_load(&slots[phase * 64 + tid], __ATOMIC_ACQUIRE, __HIP_MEMORY_SCOPE_AGENT) != val)
            __builtin_amdgcn_s_sleep(1);
    }
    __syncthreads();
}

// ---- build: convert + hist + scan + scatter(csr32 with fp16 wt), ONE dispatch ----
__global__ __launch_bounds__(1024) void build_kernel(
        const int* __restrict__ src, const int* __restrict__ dst,
        const float* __restrict__ x, const float* __restrict__ W,
        unsigned int* __restrict__ xh, unsigned int* __restrict__ Wh,
        int* __restrict__ ghist, int* __restrict__ blocksum,
        int* __restrict__ rowptr, float* __restrict__ dinv,
        unsigned int* __restrict__ csr32, int* __restrict__ bar,
        int N, int E, int Ec, int NH, int NW, int C) {
    extern __shared__ int lds[];           // N ints (40 KB)
    __shared__ int s_scan[18];
    int c = blockIdx.x;
    int tid = threadIdx.x;
    int lane = tid & 63, wv = tid >> 6;

    // P0: zero hist; grid-stride convert x,W; histogram my chunk (LDS atomics)
    for (int i = tid; i < N; i += 1024) lds[i] = 0;
    int gs = gridDim.x * 1024;
    int tot = NH + NW;
    for (int i = c * 1024 + tid; i < tot; i += gs) {
        if (i < NH) {
            float2 v = ((const float2*)x)[i];
            xh[i] = (unsigned int)f2h(v.x) | ((unsigned int)f2h(v.y) << 16);
        } else {
            float2 v = ((const float2*)W)[i - NH];
            Wh[i - NH] = (unsigned int)f2h(v.x) | ((unsigned int)f2h(v.y) << 16);
        }
    }
    __syncthreads();
    int lo = c * Ec, hi = min(lo + Ec, E);
    for (int i = lo + tid; i < hi; i += 1024)
        atomicAdd(&lds[dst[i]], 1);
    __syncthreads();
    for (int i = tid; i < N; i += 1024) ghist[c * N + i] = lds[i];
    flagbar(bar, c, C, 0);

    // P1: per-node chunk-exclusive (in place) -> deg, dinv; block-local rowptr scan
    int nper = (N + C - 1) / C;
    int n0 = c * nper;
    int nn = min(nper, N - n0); if (nn < 0) nn = 0;
    int mydeg = 0;
    if (tid < nn) {
        int n = n0 + tid;
        int run = 0;
        #pragma unroll 8
        for (int cc = 0; cc < C; cc++) {
            int t = ghist[cc * N + n];
            ghist[cc * N + n] = run;
            run += t;
        }
        mydeg = run;
        dinv[n] = rsqrtf((float)(run + 1));   // +1 self-loop
    }
    int incl = mydeg;
    #pragma unroll
    for (int off = 1; off < 64; off <<= 1) {
        int y = __shfl_up(incl, off);
        if (lane >= off) incl += y;
    }
    if (lane == 63) s_scan[wv] = incl;
    __syncthreads();
    if (tid == 0) {
        int run = 0;
        #pragma unroll
        for (int k = 0; k < 16; k++) { int t = s_scan[k]; s_scan[k] = run; run += t; }
        blocksum[c] = run;
    }
    __syncthreads();
    if (tid < nn) rowptr[n0 + tid] = s_scan[wv] + incl - mydeg;  // local prefix
    flagbar(bar, c, C, 1);

    // P2: cross-block prefix (one wave), finalize rowptr
    if (tid < 64) {
        int bs = (tid < C) ? blocksum[tid] : 0;
        int inc2 = bs;
        #pragma unroll
        for (int off = 1; off < 64; off <<= 1) {
            int y = __shfl_up(inc2, off);
            if (tid >= off) inc2 += y;
        }
        if (tid == C - 1) s_scan[16] = inc2;       // grand total
        if (tid == c)     s_scan[17] = inc2 - bs;  // my base
    }
    __syncthreads();
    int base = s_scan[17];
    if (tid < nn) rowptr[n0 + tid] += base;
    if (c == C - 1 && tid == 0) rowptr[N] = s_scan[16];
    flagbar(bar, c, C, 2);

    // P3: scatter my chunk via LDS cursors; store (src u16 | wt fp16 << 16)
    for (int i = tid; i < N; i += 1024) lds[i] = rowptr[i] + ghist[c * N + i];
    __syncthreads();
    for (int i = lo + tid; i < hi; i += 1024) {
        int d = dst[i], s = src[i];
        int pos = atomicAdd(&lds[d], 1);
        float wt = dinv[s] * dinv[d];
        csr32[pos] = (unsigned int)s | ((unsigned int)f2h(wt) << 16);
    }
}

// ---- fused3: 1 wave/node, uniform predicated 64-chunks, readlane broadcasts ----
__global__ __launch_bounds__(512) void fused3(const unsigned int* __restrict__ xh,
                                              const unsigned int* __restrict__ Wh,
                                              const int* __restrict__ rowptr,
                                              const unsigned int* __restrict__ csr32,
                                              const float* __restrict__ dinv,
                                              const float* __restrict__ bias,
                                              const float* __restrict__ gamma,
                                              const float* __restrict__ beta,
                                              float* __restrict__ out, int N) {
    int wv = threadIdx.x >> 6, lane = threadIdx.x & 63;
    int node = blockIdx.x * 8 + wv;
    if (node >= N) return;
    float dn = dinv[node];

    // self-loop
    unsigned int xv = xh[node * 64 + lane];
    float a0 = h2f((unsigned short)xv) * dn * dn;
    float a1 = h2f((unsigned short)(xv >> 16)) * dn * dn;

    // neighbor aggregation: every chunk uniform 64-wide; out-of-range lanes
    // carry pk=0 (src 0, wt 0) -> harmless hot-row gather, zero fma.
    int start = rowptr[node], end = rowptr[node + 1];
    for (int bs = start; bs < end; bs += 64) {
        int idx = bs + lane;
        unsigned int pk = (idx < end) ? csr32[idx] : 0u;
        #pragma unroll 8
        for (int k = 0; k < 64; k++) {
            unsigned int u = (unsigned int)__builtin_amdgcn_readlane((int)pk, k); // SGPR
            int sk = (int)(u & 0xffffu);
            float wk = h2f((unsigned short)(u >> 16));
            unsigned int hv = xh[sk * 64 + lane];   // scalar-base row load
            a0 += h2f((unsigned short)hv) * wk;
            a1 += h2f((unsigned short)(hv >> 16)) * wk;
        }
    }

    // linear: y[n] = sum_k agg[k]*W[k][n] + b[n]; Wh 32 KB -> L1-resident
    int c0 = lane * 2;
    float y0 = bias[c0], y1 = bias[c0 + 1];
    int ia0 = __builtin_bit_cast(int, a0), ia1 = __builtin_bit_cast(int, a1);
    #pragma unroll 8
    for (int k = 0; k < 64; k++) {
        float g0 = __builtin_bit_cast(float, __builtin_amdgcn_readlane(ia0, k));
        float g1 = __builtin_bit_cast(float, __builtin_amdgcn_readlane(ia1, k));
        unsigned int w0 = Wh[(2 * k) * 64 + lane];
        unsigned int w1 = Wh[(2 * k + 1) * 64 + lane];
        y0 += g0 * h2f((unsigned short)w0) + g1 * h2f((unsigned short)w1);
        y1 += g0 * h2f((unsigned short)(w0 >> 16)) + g1 * h2f((unsigned short)(w1 >> 16));
    }

    // LayerNorm over 128 (2 per lane)
    float sum = y0 + y1, sq = y0 * y0 + y1 * y1;
    #pragma unroll
    for (int off = 32; off > 0; off >>= 1) {
        sum += __shfl_xor(sum, off);
        sq  += __shfl_xor(sq, off);
    }
    float mean = sum * (1.0f / D);
    float var  = sq * (1.0f / D) - mean * mean;
    float inv  = rsqrtf(var + LN_EPS);
    float o0 = (y0 - mean) * inv * gamma[c0] + beta[c0];
    float o1 = (y1 - mean) * inv * gamma[c0 + 1] + beta[c0 + 1];
    *(float2*)(out + (size_t)node * D + c0) = make_float2(o0, o1);
}

// ================= fallback (R8, proven): used only if ws too small =========

__global__ void deg_kernel(const int* __restrict__ dst, int* __restrict__ deg, int E) {
    int e = blockIdx.x * blockDim.x + threadIdx.x;
    if (e < E) atomicAdd(&deg[dst[e]], 1);
}
__global__ __launch_bounds__(1024) void scan_kernel(const int* __restrict__ deg,
                                                    int* __restrict__ rowptr,
                                                    int* __restrict__ fill,
                                                    float* __restrict__ dinv, int N) {
    __shared__ int s_wsum[16];
    __shared__ int s_woff[16];
    __shared__ int s_carry;
    int t = threadIdx.x;
    int lane = t & 63, w = t >> 6;
    if (t == 0) s_carry = 0;
    __syncthreads();
    for (int base = 0; base < N; base += 1024) {
        int i = base + t;
        int v = (i < N) ? deg[i] : 0;
        int incl = v;
        #pragma unroll
        for (int off = 1; off < 64; off <<= 1) {
            int y = __shfl_up(incl, off);
            if (lane >= off) incl += y;
        }
        if (lane == 63) s_wsum[w] = incl;
        __syncthreads();
        if (t == 0) {
            int run = s_carry;
            #pragma unroll
            for (int k = 0; k < 16; k++) { s_woff[k] = run; run += s_wsum[k]; }
            s_carry = run;
        }
        __syncthreads();
        if (i < N) {
            int rp = s_woff[w] + (incl - v);
            rowptr[i] = rp;
            fill[i] = rp;
            dinv[i] = rsqrtf((float)(v + 1));
        }
    }
    if (t == 0) rowptr[N] = s_carry;
}
__global__ void fill_kernel(const int* __restrict__ src, const int* __restrict__ dst,
                            int* __restrict__ fill, unsigned short* __restrict__ csr, int E) {
    int e = blockIdx.x * blockDim.x + threadIdx.x;
    if (e < E) {
        int pos = atomicAdd(&fill[dst[e]], 1);
        csr[pos] = (unsigned short)src[e];
    }
}
__global__ __launch_bounds__(512) void fused_fp32(const float* __restrict__ x,
                                                  const float* __restrict__ W,
                                                  const int* __restrict__ rowptr,
                                                  const unsigned short* __restrict__ csr,
                                                  const float* __restrict__ dinv,
                                                  const float* __restrict__ bias,
                                                  const float* __restrict__ gamma,
                                                  const float* __restrict__ beta,
                                                  float* __restrict__ out, int N) {
    __shared__ float sW[D * D];
    {
        const float4* Wv = (const float4*)W;
        float4* sWv = (float4*)sW;
        #pragma unroll
        for (int i = 0; i < (D * D / 4) / 512; i++)
            sWv[threadIdx.x + i * 512] = Wv[threadIdx.x + i * 512];
    }
    __syncthreads();
    int w = threadIdx.x >> 6, lane = threadIdx.x & 63;
    int node = blockIdx.x * 8 + w;
    if (node >= N) return;
    float dn = dinv[node];
    int c0 = lane * 2;
    float2 xv = *(const float2*)(x + (size_t)node * D + c0);
    float a0 = xv.x * dn * dn, a1 = xv.y * dn * dn;
    int start = rowptr[node], end = rowptr[node + 1];
    int base = start;
    for (; base + 64 <= end; base += 64) {
        int s = csr[base + lane];
        float wt = dinv[s] * dn;
        #pragma unroll 8
        for (int k = 0; k < 64; k++) {
            int sk = __shfl(s, k);
            float wk = __shfl(wt, k);
            float2 xs = *(const float2*)(x + (size_t)sk * D + c0);
            a0 += xs.x * wk; a1 += xs.y * wk;
        }
    }
    int rem = end - base;
    if (rem > 0) {
        int s = 0; float wt = 0.f;
        if (lane < rem) { s = csr[base + lane]; wt = dinv[s] * dn; }
        for (int k = 0; k < rem; k++) {
            int sk = __shfl(s, k);
            float wk = __shfl(wt, k);
            float2 xs = *(const float2*)(x + (size_t)sk * D + c0);
            a0 += xs.x * wk; a1 += xs.y * wk;
        }
    }
    float y0 = bias[c0], y1 = bias[c0 + 1];
    #pragma unroll 8
    for (int k = 0; k < 64; k++) {
        float g0 = __shfl(a0, k);
        float g1 = __shfl(a1, k);
        float2 w0 = *(const float2*)(sW + (2 * k) * D + c0);
        float2 w1 = *(const float2*)(sW + (2 * k + 1) * D + c0);
        y0 += g0 * w0.x + g1 * w1.x;
        y1 += g0 * w0.y + g1 * w1.y;
    }
    float sum = y0 + y1, sq = y0 * y0 + y1 * y1;
    #pragma unroll
    for (int off = 32; off > 0; off >>= 1) {
        sum += __shfl_xor(sum, off);
        sq  += __shfl_xor(sq, off);
    }
    float mean = sum * (1.0f / D);
    float var  = sq * (1.0f / D) - mean * mean;
    float inv  = rsqrtf(var + LN_EPS);
    float o0 = (y0 - mean) * inv * gamma[c0] + beta[c0];
    float o1 = (y1 - mean) * inv * gamma[c0 + 1] + beta[c0 + 1];
    *(float2*)(out + (size_t)node * D + c0) = make_float2(o0, o1);
}

extern "C" void kernel_launch(void* const* d_in, const int* in_sizes, int n_in,
                              void* d_out, int out_size, void* d_ws, size_t ws_size,
                              hipStream_t stream) {
    const float* x     = (const float*)d_in[0];
    const int*   ei    = (const int*)d_in[1];
    const float* W     = (const float*)d_in[2];
    const float* bias  = (const float*)d_in[3];
    const float* gamma = (const float*)d_in[4];
    const float* beta  = (const float*)d_in[5];
    float*       out   = (float*)d_out;

    int N = in_sizes[0] / D;
    int E = in_sizes[1] / 2;
    const int* src = ei;
    const int* dst = ei + E;

    char* ws = (char*)d_ws;
    size_t off = 0;
    auto carve = [&](size_t bytes) { size_t p = off; off = (off + bytes + 15) & ~15UL; return (void*)(ws + p); };
    int*          bar      = (int*)         carve(3 * 64 * 4);
    int*          blocksum = (int*)         carve(64 * 4);
    int*          rowptr   = (int*)         carve((size_t)(N + 1) * 4);
    float*        dinv     = (float*)       carve((size_t)N * 4);
    unsigned int* csr32    = (unsigned int*)carve((size_t)E * 4);
    unsigned int* xh       = (unsigned int*)carve((size_t)N * (D / 2) * 4);
    unsigned int* Wh       = (unsigned int*)carve((size_t)D * (D / 2) * 4);
    size_t fixed_end = off;

    // chunk count C = grid of build_kernel; each chunk needs N*4 B of ghist.
    int C = 0;
    if (ws_size > fixed_end + 16) {
        size_t avail = ws_size - fixed_end - 16;
        size_t cmax = avail / ((size_t)N * 4);
        C = (int)((cmax > 64) ? 64 : cmax);
    }

    if (C >= 16) {
        int* ghist = (int*)carve((size_t)C * N * 4);
        int Ec = (E + C - 1) / C;
        int NH = N * (D / 2);
        int NW = D * (D / 2);
        size_t lds = (size_t)N * 4;
        hipMemsetAsync(bar, 0, 3 * 64 * 4, stream);   // flag slots
        build_kernel<<<C, 1024, lds, stream>>>(src, dst, x, W, xh, Wh, ghist,
                                               blocksum, rowptr, dinv, csr32, bar,
                                               N, E, Ec, NH, NW, C);
        fused3<<<(N + 7) / 8, 512, 0, stream>>>(xh, Wh, rowptr, csr32, dinv,
                                                bias, gamma, beta, out, N);
    } else {
        // fallback: proven R8 path
        int* deg  = (int*)carve((size_t)N * 4);
        int* fill = (int*)carve((size_t)N * 4);
        unsigned short* csr = (unsigned short*)csr32;   // reuse (E*2 <= E*4)
        hipMemsetAsync(deg, 0, (size_t)N * 4, stream);
        deg_kernel<<<(E + 255) / 256, 256, 0, stream>>>(dst, deg, E);
        scan_kernel<<<1, 1024, 0, stream>>>(deg, rowptr, fill, dinv, N);
        fill_kernel<<<(E + 255) / 256, 256, 0, stream>>>(src, dst, fill, csr, E);
        fused_fp32<<<(N + 7) / 8, 512, 0, stream>>>(x, W, rowptr, csr, dinv,
                                                    bias, gamma, beta, out, N);
    }
}